// Round 2
// baseline (932.379 us; speedup 1.0000x reference)
//
#include <hip/hip_runtime.h>
#include <math.h>
#include <stdint.h>

// R2: fix R1's two template violations.
//  (a) drop ALL sched_barrier(0) fences (m141: order-pinning = 510 TF; m201's
//      verified 8-phase uses plain s_barrier with compiler-visible ds_reads).
//  (b) XCD swizzle now gives each XCD 2 nt-tiles (W slice 1.6-3.1 MB, L2-resident,
//      disjoint across XCDs) x all mt (A panels L3-served, shared by the 2 nt
//      neighbors in L2). R1's 4mt x 16nt mapping put 25 MB of W per XCD -> L2
//      thrash -> FETCH 333->670 MB -> vmcnt stalls.
//  (c) epilogue c-exchange XOR-swizzled (was a 16-way bank conflict, ~all of the
//      remaining 5.5e6 conflict cycles).

#define DI static __device__ __forceinline__

typedef __bf16 bf16x8 __attribute__((ext_vector_type(8)));
typedef float f32x4 __attribute__((ext_vector_type(4)));
typedef float float4v __attribute__((ext_vector_type(4)));
typedef unsigned short u16;
typedef unsigned short u16x4 __attribute__((ext_vector_type(4)));

DI float b2f(u16 s) {
    unsigned u = ((unsigned)s) << 16;
    float f;
    __builtin_memcpy(&f, &u, 4);
    return f;
}
DI u16 f2b(float f) {
    unsigned x;
    __builtin_memcpy(&x, &f, 4);
    unsigned r = x + 0x7FFFu + ((x >> 16) & 1u);
    return (u16)(r >> 16);
}

// async global->LDS, 16B/lane; LDS dest = wave-uniform base + lane*16 (linear!)
DI void gl_lds(const u16* g, u16* l) {
    __builtin_amdgcn_global_load_lds(
        (__attribute__((address_space(1))) void*)g,
        (__attribute__((address_space(3))) void*)l,
        16, 0, 0);
}

DI float fast_tanh(float x) {
    float xc = fminf(fmaxf(x, -15.f), 15.f);
    float e = __expf(2.0f * xc);
    return (e - 1.f) / (e + 1.f);
}

// ============ pack kernels (unchanged) ============
__global__ void pack_A(const float* __restrict__ inp, const float* __restrict__ hx,
                       u16* __restrict__ Ahi, u16* __restrict__ Alo) {
    const int r = blockIdx.x;
    const int k = threadIdx.x * 4;
    float4v v = (k < 1024) ? *(const float4v*)(inp + (size_t)r * 1024 + k)
                           : *(const float4v*)(hx + (size_t)r * 512 + (k - 1024));
    u16x4 h, l;
#pragma unroll
    for (int e = 0; e < 4; ++e) {
        h[e] = f2b(v[e]);
        l[e] = f2b(v[e] - b2f(h[e]));
    }
    *(u16x4*)(Ahi + (size_t)r * 1536 + k) = h;
    *(u16x4*)(Alo + (size_t)r * 1536 + k) = l;
}

// Whi all 8192 gate-rows; Wlo compacted: rows [0,2048)=i-lo, [2048,4096)=c-lo.
__global__ void pack_W(const float* __restrict__ wx, const float* __restrict__ wh,
                       u16* __restrict__ Whi, u16* __restrict__ Wlo) {
    const int g = blockIdx.x;
    const int k = threadIdx.x * 4;
    float4v v = (k < 1024) ? *(const float4v*)(wx + (size_t)g * 1024 + k)
                           : *(const float4v*)(wh + (size_t)g * 512 + (k - 1024));
    u16x4 h, l;
#pragma unroll
    for (int e = 0; e < 4; ++e) {
        h[e] = f2b(v[e]);
        l[e] = f2b(v[e] - b2f(h[e]));
    }
    *(u16x4*)(Whi + (size_t)g * 1536 + k) = h;
    int lr = -1;
    if (g < 2048) lr = g;
    else if (g >= 4096 && g < 6144) lr = g - 2048;
    if (lr >= 0) *(u16x4*)(Wlo + (size_t)lr * 1536 + k) = l;
}

__global__ void pack_flat_bf16(const float* __restrict__ src, u16* __restrict__ dst) {
    const size_t t = ((size_t)blockIdx.x * blockDim.x + threadIdx.x) * 4;
    float4v v = *(const float4v*)(src + t);
    u16x4 o;
#pragma unroll
    for (int e = 0; e < 4; ++e) o[e] = f2b(v[e]);
    *(u16x4*)(dst + t) = o;
}

// ============ 8-phase 256x256 GEMM core ============
// Geometry: BM=BN=256, BK=64, 512 thr = 8 waves (2M x 4N), per-wave 128x64 out.
// LDS 128 KiB: A[2buf][256][64]u16 @0, W[2buf][256][64]u16 @32768 (u16 idx).
// T2 swizzle: within each 128B row, 16B-chunk c stored at c ^ (row&7)
//   (linear LDS dest for gl_lds, inverse-swizzled global SOURCE, swizzled read).
// Region-safety: every LDS region's reads complete >=2 barriers before its
// overwrite (so compiler hoist-by-one-interval is harmless; no sched fences).
// vmcnt: 2 gl_lds/phase/wave; VMCNT(4) at P4 (tile t+1 landed) and P8 (t+2
// landed); never drains to 0 in steady state (T4).

#define VMCNT(n) asm volatile("s_waitcnt vmcnt(" #n ")" ::: "memory")
#define PH_BAR() __builtin_amdgcn_s_barrier()

#define LDA_(b, mh)                                                                   \
    do {                                                                              \
        _Pragma("unroll") for (int i_ = 0; i_ < 4; ++i_) {                            \
            Af[i_][0] = *(const bf16x8*)(pA + (b)*16384 + ((mh)*4 + i_) * 1024 + cs0);\
            Af[i_][1] = *(const bf16x8*)(pA + (b)*16384 + ((mh)*4 + i_) * 1024 + cs1);\
        }                                                                             \
    } while (0)

#define LDW_(b, jj)                                                                   \
    do {                                                                              \
        _Pragma("unroll") for (int j_ = 0; j_ < 2; ++j_) {                            \
            Wf[(jj)*2 + j_][0] =                                                      \
                *(const bf16x8*)(pW + (b)*16384 + ((jj)*2 + j_) * 1024 + cs0);        \
            Wf[(jj)*2 + j_][1] =                                                      \
                *(const bf16x8*)(pW + (b)*16384 + ((jj)*2 + j_) * 1024 + cs1);        \
        }                                                                             \
    } while (0)

#define MFMAQ(mh, nh)                                                                 \
    do {                                                                              \
        __builtin_amdgcn_s_setprio(1);                                                \
        _Pragma("unroll") for (int i_ = 0; i_ < 4; ++i_) {                            \
            _Pragma("unroll") for (int j_ = 0; j_ < 2; ++j_) {                        \
                acc[(mh)*4 + i_][(nh)*2 + j_] =                                       \
                    __builtin_amdgcn_mfma_f32_16x16x32_bf16(                          \
                        Af[i_][0], Wf[(nh)*2 + j_][0],                                \
                        acc[(mh)*4 + i_][(nh)*2 + j_], 0, 0, 0);                      \
                acc[(mh)*4 + i_][(nh)*2 + j_] =                                       \
                    __builtin_amdgcn_mfma_f32_16x16x32_bf16(                          \
                        Af[i_][1], Wf[(nh)*2 + j_][1],                                \
                        acc[(mh)*4 + i_][(nh)*2 + j_], 0, 0, 0);                      \
            }                                                                         \
        }                                                                             \
        __builtin_amdgcn_s_setprio(0);                                                \
    } while (0)

// Prologue: tile0 (4 half-tiles) + tile1 {W-h0, A-h0}; vmcnt(4) => tile0 landed.
#define GEMM8_LOOP(NI_, SA, SW)                                                       \
    SA(0, 0, 0);                                                                      \
    SA(0, 0, 1);                                                                      \
    SW(0, 0, 0);                                                                      \
    SW(0, 0, 1);                                                                      \
    SW(1, 1, 0);                                                                      \
    SA(1, 1, 0);                                                                      \
    VMCNT(4);                                                                         \
    PH_BAR();                                                                         \
    for (int I_ = 0; I_ < (NI_); ++I_) {                                              \
        const int t_ = 2 * I_;                                                        \
        const bool more_ = (I_ < (NI_)-1);                                            \
        /* P1 */                                                                      \
        LDA_(0, 0);                                                                   \
        LDW_(0, 0);                                                                   \
        SW(1, t_ + 1, 1);                                                             \
        PH_BAR();                                                                     \
        MFMAQ(0, 0);                                                                  \
        PH_BAR();                                                                     \
        /* P2 */                                                                      \
        LDW_(0, 1);                                                                   \
        SA(1, t_ + 1, 1);                                                             \
        PH_BAR();                                                                     \
        MFMAQ(0, 1);                                                                  \
        PH_BAR();                                                                     \
        /* P3 */                                                                      \
        LDA_(0, 1);                                                                   \
        if (more_) SW(0, t_ + 2, 0);                                                  \
        PH_BAR();                                                                     \
        MFMAQ(1, 0);                                                                  \
        PH_BAR();                                                                     \
        /* P4 */                                                                      \
        if (more_) SW(0, t_ + 2, 1);                                                  \
        PH_BAR();                                                                     \
        MFMAQ(1, 1);                                                                  \
        if (more_) { VMCNT(4); } else { VMCNT(0); }                                   \
        PH_BAR();                                                                     \
        /* P5 */                                                                      \
        LDA_(1, 0);                                                                   \
        LDW_(1, 0);                                                                   \
        if (more_) SA(0, t_ + 2, 0);                                                  \
        PH_BAR();                                                                     \
        MFMAQ(0, 0);                                                                  \
        PH_BAR();                                                                     \
        /* P6 */                                                                      \
        LDW_(1, 1);                                                                   \
        if (more_) SA(0, t_ + 2, 1);                                                  \
        PH_BAR();                                                                     \
        MFMAQ(0, 1);                                                                  \
        PH_BAR();                                                                     \
        /* P7 */                                                                      \
        LDA_(1, 1);                                                                   \
        if (more_) SW(1, t_ + 3, 0);                                                  \
        PH_BAR();                                                                     \
        MFMAQ(1, 0);                                                                  \
        PH_BAR();                                                                     \
        /* P8 */                                                                      \
        if (more_) SA(1, t_ + 3, 0);                                                  \
        PH_BAR();                                                                     \
        MFMAQ(1, 1);                                                                  \
        if (more_) {                                                                  \
            VMCNT(4);                                                                 \
            PH_BAR();                                                                 \
        }                                                                             \
    }

// T1 swizzle: XCD = id&7 owns nt in {2*xcd, 2*xcd+1} (disjoint L2-resident W
// slice) and streams all mt; the nt-pair (adjacent ids) shares each A panel.
DI void swz512(int id, int& mt, int& nt) {
    nt = (id & 7) * 2 + ((id >> 3) & 1);
    mt = id >> 4;
}

// ============ G1: f,o gates, plain bf16, 8-phase ============
__global__ __launch_bounds__(512, 2) void gemm8_fo(const u16* __restrict__ A,
                                                   const u16* __restrict__ W,
                                                   const float* __restrict__ bxv,
                                                   const float* __restrict__ bhv,
                                                   u16* __restrict__ out) {
    constexpr int NKT = 24, NI = NKT / 2;
    __shared__ u16 sm[65536];  // 128 KiB

    const int tid = threadIdx.x, wid = tid >> 6, lane = tid & 63;
    const int wm = wid >> 2, wn = wid & 3;
    int mt, nt;
    swz512(blockIdx.x, mt, nt);
    const size_t rowA0 = (size_t)mt * 256;
    const size_t rowW0 = (nt < 8) ? (2048 + (size_t)nt * 256) : (4096 + (size_t)nt * 256);

    // staging lane constants (inverse swizzle on global source)
    const int rl = lane >> 3;
    const int cl8 = ((lane & 7) ^ rl) * 8;
    // frag-read constants (swizzled chunk offsets, in u16)
    const int r15 = lane & 15, q4 = lane >> 4, x7 = lane & 7;
    const int cs0 = (q4 ^ x7) * 8;
    const int cs1 = ((q4 + 4) ^ x7) * 8;
    u16* pA = sm + ((size_t)wm * 128 + r15) * 64;
    u16* pW = sm + 32768 + ((size_t)wn * 64 + r15) * 64;

#define STG_A_FO(b, kt, hh)                                                           \
    do {                                                                              \
        const u16* s_ = A + (rowA0 + (hh)*128 + wid * 8 + rl) * (size_t)1536 +        \
                        (kt)*64 + cl8;                                                \
        u16* d_ = sm + (b)*16384 + ((hh)*128 + wid * 8) * 64;                         \
        gl_lds(s_, d_);                                                               \
        gl_lds(s_ + (size_t)64 * 1536, d_ + 4096);                                    \
    } while (0)
#define STG_W_FO(b, kt, hh)                                                           \
    do {                                                                              \
        const u16* s_ = W + (rowW0 + (hh)*128 + wid * 8 + rl) * (size_t)1536 +        \
                        (kt)*64 + cl8;                                                \
        u16* d_ = sm + 32768 + (b)*16384 + ((hh)*128 + wid * 8) * 64;                 \
        gl_lds(s_, d_);                                                               \
        gl_lds(s_ + (size_t)64 * 1536, d_ + 4096);                                    \
    } while (0)

    f32x4 acc[8][4] = {};
    bf16x8 Af[4][2], Wf[4][2];

    GEMM8_LOOP(NI, STG_A_FO, STG_W_FO);
#undef STG_A_FO
#undef STG_W_FO

    // epilogue: bias + bf16 store to Gfo[B,4096]
    const size_t mBase = (size_t)mt * 256 + wm * 128;
#pragma unroll
    for (int j = 0; j < 4; ++j) {
        const size_t n = (size_t)nt * 256 + wn * 64 + j * 16 + r15;
        const size_t g = (n < 2048) ? (2048 + n) : (4096 + n);
        const float bias = bxv[g] + bhv[g];
#pragma unroll
        for (int i = 0; i < 8; ++i) {
            const size_t m0 = mBase + i * 16 + q4 * 4;
#pragma unroll
            for (int v = 0; v < 4; ++v)
                out[(m0 + v) * 4096 + n] = f2b(acc[i][j][v] + bias);
        }
    }
}

// ============ G2: i,c as one K=4608 GEMM + fused cell, 8-phase ============
// A' = [Ahi | Alo | Ahi] (kt/24 selects plane); W' half0 = i-rows, half1 = c-rows
// (Whi for kt<48, Wlo for kt>=48). Tile nt covers h in [nt*128,(nt+1)*128):
// cols 0..127 = i, 128..255 = c, so the cell fuses per-block via an LDS exchange.
__global__ __launch_bounds__(512, 2) void gemm8_ic_cell(
    const u16* __restrict__ Ahi, const u16* __restrict__ Alo,
    const u16* __restrict__ Whi, const u16* __restrict__ Wlo,
    const float* __restrict__ bxv, const float* __restrict__ bhv,
    const u16* __restrict__ Gfo, const float* __restrict__ cx,
    float* __restrict__ ct, u16* __restrict__ U) {
    constexpr int NKT = 72, NI = NKT / 2;  // 3 x 24 K-tiles (hi*hi, lo*hi, hi*lo)
    __shared__ u16 sm[65536];  // 128 KiB; reused as float c-buffer in epilogue

    const int tid = threadIdx.x, wid = tid >> 6, lane = tid & 63;
    const int wm = wid >> 2, wn = wid & 3;
    int mt, nt;
    swz512(blockIdx.x, mt, nt);
    const size_t rowA0 = (size_t)mt * 256;
    const size_t h0t = (size_t)nt * 128;

    const int rl = lane >> 3;
    const int cl8 = ((lane & 7) ^ rl) * 8;
    const int r15 = lane & 15, q4 = lane >> 4, x7 = lane & 7;
    const int cs0 = (q4 ^ x7) * 8;
    const int cs1 = ((q4 + 4) ^ x7) * 8;
    u16* pA = sm + ((size_t)wm * 128 + r15) * 64;
    u16* pW = sm + 32768 + ((size_t)wn * 64 + r15) * 64;

#define STG_A_IC(b, kt, hh)                                                           \
    do {                                                                              \
        const int p_ = (kt) / 24;                                                     \
        const int kc_ = ((kt) % 24) * 64;                                             \
        const u16* base_ = (p_ == 1) ? Alo : Ahi;                                     \
        const u16* s_ = base_ + (rowA0 + (hh)*128 + wid * 8 + rl) * (size_t)1536 +    \
                        kc_ + cl8;                                                    \
        u16* d_ = sm + (b)*16384 + ((hh)*128 + wid * 8) * 64;                         \
        gl_lds(s_, d_);                                                               \
        gl_lds(s_ + (size_t)64 * 1536, d_ + 4096);                                    \
    } while (0)
#define STG_W_IC(b, kt, hh)                                                           \
    do {                                                                              \
        const int kc_ = ((kt) % 24) * 64;                                             \
        const u16* wp_ = ((kt) < 48) ? Whi : Wlo;                                     \
        const size_t rb_ = h0t + ((hh) ? (((kt) < 48) ? (size_t)4096 : (size_t)2048)  \
                                       : (size_t)0);                                  \
        const u16* s_ = wp_ + (rb_ + wid * 8 + rl) * (size_t)1536 + kc_ + cl8;        \
        u16* d_ = sm + 32768 + (b)*16384 + ((hh)*128 + wid * 8) * 64;                 \
        gl_lds(s_, d_);                                                               \
        gl_lds(s_ + (size_t)64 * 1536, d_ + 4096);                                    \
    } while (0)

    f32x4 acc[8][4] = {};
    bf16x8 Af[4][2], Wf[4][2];

    GEMM8_LOOP(NI, STG_A_IC, STG_W_IC);
#undef STG_A_IC
#undef STG_W_IC

    // ---- fused LSTM cell epilogue ----
    // c-waves (wn>=2) publish c (+bias) via LDS; i-waves (wn<2) fuse the cell.
    // Exchange XOR-swizzled: chunk moff ^ ((hl&7)*4) -> 2-way banks (was 16-way).
    __syncthreads();  // all waves done with K-loop LDS before reuse
    float* cb = (float*)sm;  // logical [128 h][256 m], swizzled
    const size_t mBase = (size_t)mt * 256 + wm * 128;
    if (wn >= 2) {
#pragma unroll
        for (int j = 0; j < 4; ++j) {
            const int hl = (wn - 2) * 64 + j * 16 + r15;
            const size_t h = h0t + hl;
            const float bc = bxv[4096 + h] + bhv[4096 + h];
#pragma unroll
            for (int i = 0; i < 8; ++i) {
                f32x4 v = acc[i][j];
                v[0] += bc; v[1] += bc; v[2] += bc; v[3] += bc;
                const int moff = wm * 128 + i * 16 + q4 * 4;
                *(f32x4*)&cb[(size_t)hl * 256 + (moff ^ ((hl & 7) * 4))] = v;
            }
        }
    }
    __syncthreads();
    if (wn < 2) {
#pragma unroll
        for (int j = 0; j < 4; ++j) {
            const int hl = wn * 64 + j * 16 + r15;
            const size_t h = h0t + hl;
            const float bi = bxv[h] + bhv[h];
#pragma unroll
            for (int i = 0; i < 8; ++i) {
                const size_t m0 = mBase + i * 16 + q4 * 4;
                const int moff = wm * 128 + i * 16 + q4 * 4;
                const f32x4 cv =
                    *(const f32x4*)&cb[(size_t)hl * 256 + (moff ^ ((hl & 7) * 4))];
#pragma unroll
                for (int v = 0; v < 4; ++v) {
                    const size_t m = m0 + v;
                    const float iv = acc[i][j][v] + bi;
                    const float f = b2f(Gfo[m * 4096 + h]);
                    const float o = b2f(Gfo[m * 4096 + 2048 + h]);
                    const float c_ = f * cx[m * 2048 + h] + iv * cv[v];
                    ct[m * 2048 + h] = c_;
                    U[m * 2048 + h] = f2b(o * fast_tanh(c_));
                }
            }
        }
    }
}

// ============ proj: ht[B,512] = U[B,2048] * Wp[512,2048]^T, dbuf (unchanged) ============
__global__ __launch_bounds__(256, 2) void gemm_proj(const u16* __restrict__ A,
                                                    const u16* __restrict__ W,
                                                    float* __restrict__ out) {
    constexpr int K = 2048, BK = 32;
    constexpr int AB = 128 * BK;
    constexpr int WB = 64 * BK;
    __shared__ u16 As[2 * AB];
    __shared__ u16 Ws[2 * WB];

    const int tid = threadIdx.x, wave = tid >> 6, lane = tid & 63;
    const size_t tileM = (size_t)blockIdx.y * 128;
    const size_t tileN = (size_t)blockIdx.x * 64;
    const int waveM = (wave >> 1) * 64;
    const int waveN = (wave & 1) * 32;

    const int srow = lane >> 2, scol = (lane & 3) * 8;
    const u16* Ag = A + (tileM + (size_t)(wave * 16 + srow)) * K + scol;
    const u16* Wg = W + (tileN + (size_t)(wave * 16 + srow)) * K + scol;
    const int lA0 = (wave * 16) * BK;
    const int lA1 = (wave * 16 + 64) * BK;

    f32x4 acc[4][2] = {};
    const int arow = waveM + (lane & 15);
    const int wrow = waveN + (lane & 15);
    const int kq = (lane >> 4) * 8;

#define STAGE_PR(b, k0)                                        \
    do {                                                       \
        gl_lds(Ag + (k0), &As[(b)*AB + lA0]);                  \
        gl_lds(Ag + (size_t)64 * K + (k0), &As[(b)*AB + lA1]); \
        gl_lds(Wg + (k0), &Ws[(b)*WB + lA0]);                  \
    } while (0)

#define COMPUTE_PR(b)                                                          \
    do {                                                                       \
        bf16x8 af[4], wf[2];                                                   \
        _Pragma("unroll") for (int i = 0; i < 4; ++i)                          \
            af[i] = *(const bf16x8*)&As[(b)*AB + (arow + i * 16) * BK + kq];   \
        _Pragma("unroll") for (int j = 0; j < 2; ++j)                          \
            wf[j] = *(const bf16x8*)&Ws[(b)*WB + (wrow + j * 16) * BK + kq];   \
        _Pragma("unroll") for (int i = 0; i < 4; ++i)                          \
            _Pragma("unroll") for (int j = 0; j < 2; ++j)                      \
                acc[i][j] = __builtin_amdgcn_mfma_f32_16x16x32_bf16(           \
                    af[i], wf[j], acc[i][j], 0, 0, 0);                         \
    } while (0)

    STAGE_PR(0, 0);
    __syncthreads();
    for (int k0 = 0; k0 < K; k0 += 2 * BK) {
        STAGE_PR(1, k0 + BK);
        COMPUTE_PR(0);
        __syncthreads();
        if (k0 + 2 * BK < K) STAGE_PR(0, k0 + 2 * BK);
        COMPUTE_PR(1);
        __syncthreads();
    }
#undef STAGE_PR
#undef COMPUTE_PR

    const int rq = (lane >> 4) * 4;
#pragma unroll
    for (int i = 0; i < 4; ++i) {
        const size_t rbase = tileM + waveM + i * 16 + rq;
#pragma unroll
        for (int j = 0; j < 2; ++j) {
            const size_t n = tileN + waveN + (lane & 15) + j * 16;
#pragma unroll
            for (int v = 0; v < 4; ++v)
                out[(rbase + v) * 512 + n] = acc[i][j][v];
        }
    }
}

// ============ launch ============
extern "C" void kernel_launch(void* const* d_in, const int* in_sizes, int n_in,
                              void* d_out, int out_size, void* d_ws, size_t ws_size,
                              hipStream_t stream) {
    const float* input  = (const float*)d_in[0];
    const float* hx     = (const float*)d_in[1];
    const float* cx     = (const float*)d_in[2];
    const float* w_x    = (const float*)d_in[3];
    const float* b_x    = (const float*)d_in[4];
    const float* w_h    = (const float*)d_in[5];
    const float* b_h    = (const float*)d_in[6];
    const float* w_proj = (const float*)d_in[7];

    constexpr int H = 2048, P = 512, B = 8192;

    char* ws = (char*)d_ws;
    u16* Ahi = (u16*)(ws);                 // [8192,1536] 25,165,824
    u16* Alo = (u16*)(ws + 25165824);      // [8192,1536] 25,165,824
    u16* Whi = (u16*)(ws + 50331648);      // [8192,1536] 25,165,824
    u16* Wlo = (u16*)(ws + 75497472);      // [4096,1536] 12,582,912
    u16* Gfo = (u16*)(ws + 88080384);      // [8192,4096] 67,108,864
    u16* U   = (u16*)(ws + 155189248);     // [8192,2048] 33,554,432
    u16* Wp  = (u16*)(ws + 188743680);     // [512,2048]   2,097,152

    float* ht = (float*)d_out;
    float* ct = (float*)d_out + (size_t)B * P;

    pack_A<<<B, 384, 0, stream>>>(input, hx, Ahi, Alo);
    pack_W<<<4 * H, 384, 0, stream>>>(w_x, w_h, Whi, Wlo);
    pack_flat_bf16<<<(P * H / 4) / 256, 256, 0, stream>>>(w_proj, Wp);

    gemm8_fo<<<512, 512, 0, stream>>>(Ahi, Whi, b_x, b_h, Gfo);
    gemm8_ic_cell<<<512, 512, 0, stream>>>(Ahi, Alo, Whi, Wlo, b_x, b_h,
                                           Gfo, cx, ct, U);
    gemm_proj<<<dim3(8, 64), 256, 0, stream>>>(U, Wp, ht);
}

// Round 3
// 642.620 us; speedup vs baseline: 1.4509x; 1.4509x over previous
//
#include <hip/hip_runtime.h>
#include <math.h>
#include <stdint.h>

// R3: revert to the PROVEN R0 2-barrier/BK=32 structure (813 TF measured on this
// problem; both 8-phase ports landed at 500-573 TF — cut that branch), and fuse
// all four gates into ONE kernel:
//   - each wave holds f,o,i,c accumulators for the same (m,h) range
//   - LSTM cell is a pure-register epilogue (Gfo 67MB store + 67MB re-read and
//     the whole gemm_fo kernel + launch are eliminated)
//   - f,o gain precision (no bf16 Gfo round-trip)
// LDS 81920 B = exactly 2 blocks/CU; W fragments scoped per-gate to cap VGPRs.

#define DI static __device__ __forceinline__

typedef __bf16 bf16x8 __attribute__((ext_vector_type(8)));
typedef float f32x4 __attribute__((ext_vector_type(4)));
typedef float float4v __attribute__((ext_vector_type(4)));
typedef unsigned short u16;
typedef unsigned short u16x4 __attribute__((ext_vector_type(4)));

DI float b2f(u16 s) {
    unsigned u = ((unsigned)s) << 16;
    float f;
    __builtin_memcpy(&f, &u, 4);
    return f;
}
DI u16 f2b(float f) {
    unsigned x;
    __builtin_memcpy(&x, &f, 4);
    unsigned r = x + 0x7FFFu + ((x >> 16) & 1u);
    return (u16)(r >> 16);
}

// async global->LDS, 16B/lane; LDS dest = wave-uniform base + lane*16
DI void gl_lds(const u16* g, u16* l) {
    __builtin_amdgcn_global_load_lds(
        (__attribute__((address_space(1))) void*)g,
        (__attribute__((address_space(3))) void*)l,
        16, 0, 0);
}

DI float fast_tanh(float x) {
    float xc = fminf(fmaxf(x, -15.f), 15.f);
    float e = __expf(2.0f * xc);
    return (e - 1.f) / (e + 1.f);
}

// ============ pack kernels (unchanged from R0) ============
__global__ void pack_A(const float* __restrict__ inp, const float* __restrict__ hx,
                       u16* __restrict__ Ahi, u16* __restrict__ Alo) {
    const int r = blockIdx.x;
    const int k = threadIdx.x * 4;
    float4v v = (k < 1024) ? *(const float4v*)(inp + (size_t)r * 1024 + k)
                           : *(const float4v*)(hx + (size_t)r * 512 + (k - 1024));
    u16x4 h, l;
#pragma unroll
    for (int e = 0; e < 4; ++e) {
        h[e] = f2b(v[e]);
        l[e] = f2b(v[e] - b2f(h[e]));
    }
    *(u16x4*)(Ahi + (size_t)r * 1536 + k) = h;
    *(u16x4*)(Alo + (size_t)r * 1536 + k) = l;
}

// Whi all 8192 gate-rows; Wlo compacted: rows [0,2048)=i-lo, [2048,4096)=c-lo.
__global__ void pack_W(const float* __restrict__ wx, const float* __restrict__ wh,
                       u16* __restrict__ Whi, u16* __restrict__ Wlo) {
    const int g = blockIdx.x;
    const int k = threadIdx.x * 4;
    float4v v = (k < 1024) ? *(const float4v*)(wx + (size_t)g * 1024 + k)
                           : *(const float4v*)(wh + (size_t)g * 512 + (k - 1024));
    u16x4 h, l;
#pragma unroll
    for (int e = 0; e < 4; ++e) {
        h[e] = f2b(v[e]);
        l[e] = f2b(v[e] - b2f(h[e]));
    }
    *(u16x4*)(Whi + (size_t)g * 1536 + k) = h;
    int lr = -1;
    if (g < 2048) lr = g;
    else if (g >= 4096 && g < 6144) lr = g - 2048;
    if (lr >= 0) *(u16x4*)(Wlo + (size_t)lr * 1536 + k) = l;
}

__global__ void pack_flat_bf16(const float* __restrict__ src, u16* __restrict__ dst) {
    const size_t t = ((size_t)blockIdx.x * blockDim.x + threadIdx.x) * 4;
    float4v v = *(const float4v*)(src + t);
    u16x4 o;
#pragma unroll
    for (int e = 0; e < 4; ++e) o[e] = f2b(v[e]);
    *(u16x4*)(dst + t) = o;
}

// ---- XCD swizzle (R0-proven: FETCH 333 MB): linear id -> (bx in [0,32), by in [0,64))
DI void swizzle2048(int id, int& bx, int& by) {
    const int xcd = id & 7;
    const int j = id >> 3;
    bx = xcd * 4 + (j & 3);
    by = j >> 2;
}

// ============ fused 4-gate GEMM + LSTM cell (R0 structure) ============
// Per block: M=128 x h=64. Gates: f,o plain bf16 (1 term); i,c split-bf16
// (3 terms: ah*wh + al*wh + ah*wl). 4 waves: (wave>>1)->M half, (wave&1)->h half.
// Per wave: acc[4m][2h] x 4 gates = 32 f32x4. K-loop: BK=32, double-buffered LDS,
// 10 gl_lds + 64 MFMA per wave per K-step.
__global__ __launch_bounds__(256, 2) void gemm_gates_cell(
    const u16* __restrict__ Ahi, const u16* __restrict__ Alo,
    const u16* __restrict__ Whi, const u16* __restrict__ Wlo,
    const float* __restrict__ bxv, const float* __restrict__ bhv,
    const float* __restrict__ cx, float* __restrict__ ct, u16* __restrict__ U) {
    constexpr int K = 1536, BK = 32;
    constexpr int AB = 128 * BK;  // 4096 elems per A buffer
    constexpr int WB = 64 * BK;   // 2048 elems per W buffer
    __shared__ u16 sAh[2 * AB], sAl[2 * AB];
    __shared__ u16 sWf[2 * WB], sWo[2 * WB];
    __shared__ u16 sWih[2 * WB], sWil[2 * WB], sWch[2 * WB], sWcl[2 * WB];
    // total = 2*8192 + 6*4096 = 40960 u16 = 81920 B -> exactly 2 blocks/CU

    const int tid = threadIdx.x, wave = tid >> 6, lane = tid & 63;
    int bxi, byi;
    swizzle2048(blockIdx.x, bxi, byi);
    const size_t tileM = (size_t)byi * 128;
    const size_t h0 = (size_t)bxi * 64;
    const int waveM = (wave >> 1) * 64;
    const int waveH = (wave & 1) * 32;

    const int srow = lane >> 2, scol = (lane & 3) * 8;
    const size_t wr = (size_t)(wave * 16 + srow);
    const u16* gAh = Ahi + (tileM + wr) * K + scol;
    const u16* gAl = Alo + (tileM + wr) * K + scol;
    // gate-row bases in Whi: i @ h, f @ 2048+h, c @ 4096+h, o @ 6144+h
    const u16* gWih = Whi + (h0 + wr) * K + scol;
    const u16* gWf  = Whi + (2048 + h0 + wr) * K + scol;
    const u16* gWch = Whi + (4096 + h0 + wr) * K + scol;
    const u16* gWo  = Whi + (6144 + h0 + wr) * K + scol;
    const u16* gWil = Wlo + (h0 + wr) * K + scol;
    const u16* gWcl = Wlo + (2048 + h0 + wr) * K + scol;
    const int lA0 = (wave * 16) * BK;
    const int lA1 = (wave * 16 + 64) * BK;
    const int lW0 = (wave * 16) * BK;

    f32x4 aF[4][2] = {}, aO[4][2] = {}, aI[4][2] = {}, aC[4][2] = {};
    const int arow = waveM + (lane & 15);
    const int wrow = waveH + (lane & 15);
    const int kq = (lane >> 4) * 8;

#define STAGE_G(b, k0)                                           \
    do {                                                         \
        gl_lds(gAh + (k0), &sAh[(b)*AB + lA0]);                  \
        gl_lds(gAh + (size_t)64 * K + (k0), &sAh[(b)*AB + lA1]); \
        gl_lds(gAl + (k0), &sAl[(b)*AB + lA0]);                  \
        gl_lds(gAl + (size_t)64 * K + (k0), &sAl[(b)*AB + lA1]); \
        gl_lds(gWf + (k0), &sWf[(b)*WB + lW0]);                  \
        gl_lds(gWo + (k0), &sWo[(b)*WB + lW0]);                  \
        gl_lds(gWih + (k0), &sWih[(b)*WB + lW0]);                \
        gl_lds(gWil + (k0), &sWil[(b)*WB + lW0]);                \
        gl_lds(gWch + (k0), &sWch[(b)*WB + lW0]);                \
        gl_lds(gWcl + (k0), &sWcl[(b)*WB + lW0]);                \
    } while (0)

#define COMPUTE_G(b)                                                              \
    do {                                                                          \
        bf16x8 ah[4], al[4];                                                      \
        _Pragma("unroll") for (int i = 0; i < 4; ++i) {                           \
            ah[i] = *(const bf16x8*)&sAh[(b)*AB + (arow + i * 16) * BK + kq];     \
            al[i] = *(const bf16x8*)&sAl[(b)*AB + (arow + i * 16) * BK + kq];     \
        }                                                                         \
        { /* f gate: 1 term */                                                    \
            bf16x8 w[2];                                                          \
            _Pragma("unroll") for (int j = 0; j < 2; ++j)                         \
                w[j] = *(const bf16x8*)&sWf[(b)*WB + (wrow + j * 16) * BK + kq];  \
            _Pragma("unroll") for (int i = 0; i < 4; ++i)                         \
                _Pragma("unroll") for (int j = 0; j < 2; ++j)                     \
                    aF[i][j] = __builtin_amdgcn_mfma_f32_16x16x32_bf16(           \
                        ah[i], w[j], aF[i][j], 0, 0, 0);                          \
        }                                                                         \
        { /* o gate: 1 term */                                                    \
            bf16x8 w[2];                                                          \
            _Pragma("unroll") for (int j = 0; j < 2; ++j)                         \
                w[j] = *(const bf16x8*)&sWo[(b)*WB + (wrow + j * 16) * BK + kq];  \
            _Pragma("unroll") for (int i = 0; i < 4; ++i)                         \
                _Pragma("unroll") for (int j = 0; j < 2; ++j)                     \
                    aO[i][j] = __builtin_amdgcn_mfma_f32_16x16x32_bf16(           \
                        ah[i], w[j], aO[i][j], 0, 0, 0);                          \
        }                                                                         \
        { /* i gate: 3 terms */                                                   \
            bf16x8 wh[2], wl[2];                                                  \
            _Pragma("unroll") for (int j = 0; j < 2; ++j) {                       \
                wh[j] = *(const bf16x8*)&sWih[(b)*WB + (wrow + j * 16) * BK + kq];\
                wl[j] = *(const bf16x8*)&sWil[(b)*WB + (wrow + j * 16) * BK + kq];\
            }                                                                     \
            _Pragma("unroll") for (int i = 0; i < 4; ++i)                         \
                _Pragma("unroll") for (int j = 0; j < 2; ++j) {                   \
                    aI[i][j] = __builtin_amdgcn_mfma_f32_16x16x32_bf16(           \
                        ah[i], wh[j], aI[i][j], 0, 0, 0);                         \
                    aI[i][j] = __builtin_amdgcn_mfma_f32_16x16x32_bf16(           \
                        al[i], wh[j], aI[i][j], 0, 0, 0);                         \
                    aI[i][j] = __builtin_amdgcn_mfma_f32_16x16x32_bf16(           \
                        ah[i], wl[j], aI[i][j], 0, 0, 0);                         \
                }                                                                 \
        }                                                                         \
        { /* c gate: 3 terms */                                                   \
            bf16x8 wh[2], wl[2];                                                  \
            _Pragma("unroll") for (int j = 0; j < 2; ++j) {                       \
                wh[j] = *(const bf16x8*)&sWch[(b)*WB + (wrow + j * 16) * BK + kq];\
                wl[j] = *(const bf16x8*)&sWcl[(b)*WB + (wrow + j * 16) * BK + kq];\
            }                                                                     \
            _Pragma("unroll") for (int i = 0; i < 4; ++i)                         \
                _Pragma("unroll") for (int j = 0; j < 2; ++j) {                   \
                    aC[i][j] = __builtin_amdgcn_mfma_f32_16x16x32_bf16(           \
                        ah[i], wh[j], aC[i][j], 0, 0, 0);                         \
                    aC[i][j] = __builtin_amdgcn_mfma_f32_16x16x32_bf16(           \
                        al[i], wh[j], aC[i][j], 0, 0, 0);                         \
                    aC[i][j] = __builtin_amdgcn_mfma_f32_16x16x32_bf16(           \
                        ah[i], wl[j], aC[i][j], 0, 0, 0);                         \
                }                                                                 \
        }                                                                         \
    } while (0)

    STAGE_G(0, 0);
    __syncthreads();
    for (int k0 = 0; k0 < K; k0 += 2 * BK) {
        STAGE_G(1, k0 + BK);
        COMPUTE_G(0);
        __syncthreads();
        if (k0 + 2 * BK < K) STAGE_G(0, k0 + 2 * BK);
        COMPUTE_G(1);
        __syncthreads();
    }
#undef STAGE_G
#undef COMPUTE_G

    // ---- fully in-register LSTM cell epilogue ----
    const int rq = (lane >> 4) * 4;
#pragma unroll
    for (int j = 0; j < 2; ++j) {
        const size_t h = h0 + waveH + j * 16 + (lane & 15);
        const float bi = bxv[h] + bhv[h];
        const float bf = bxv[2048 + h] + bhv[2048 + h];
        const float bc = bxv[4096 + h] + bhv[4096 + h];
        const float bo = bxv[6144 + h] + bhv[6144 + h];
#pragma unroll
        for (int i = 0; i < 4; ++i) {
            const size_t m0 = tileM + waveM + i * 16 + rq;
#pragma unroll
            for (int v = 0; v < 4; ++v) {
                const size_t m = m0 + v;
                const float fv = aF[i][j][v] + bf;
                const float ov = aO[i][j][v] + bo;
                const float iv = aI[i][j][v] + bi;
                const float cv = aC[i][j][v] + bc;
                const float c_ = fv * cx[m * 2048 + h] + iv * cv;
                ct[m * 2048 + h] = c_;
                U[m * 2048 + h] = f2b(ov * fast_tanh(c_));
            }
        }
    }
}

// ============ proj: ht[B,512] = U[B,2048] * Wp[512,2048]^T, dbuf (unchanged) ============
__global__ __launch_bounds__(256, 2) void gemm_proj(const u16* __restrict__ A,
                                                    const u16* __restrict__ W,
                                                    float* __restrict__ out) {
    constexpr int K = 2048, BK = 32;
    constexpr int AB = 128 * BK;
    constexpr int WB = 64 * BK;
    __shared__ u16 As[2 * AB];
    __shared__ u16 Ws[2 * WB];

    const int tid = threadIdx.x, wave = tid >> 6, lane = tid & 63;
    const size_t tileM = (size_t)blockIdx.y * 128;
    const size_t tileN = (size_t)blockIdx.x * 64;
    const int waveM = (wave >> 1) * 64;
    const int waveN = (wave & 1) * 32;

    const int srow = lane >> 2, scol = (lane & 3) * 8;
    const u16* Ag = A + (tileM + (size_t)(wave * 16 + srow)) * K + scol;
    const u16* Wg = W + (tileN + (size_t)(wave * 16 + srow)) * K + scol;
    const int lA0 = (wave * 16) * BK;
    const int lA1 = (wave * 16 + 64) * BK;

    f32x4 acc[4][2] = {};
    const int arow = waveM + (lane & 15);
    const int wrow = waveN + (lane & 15);
    const int kq = (lane >> 4) * 8;

#define STAGE_PR(b, k0)                                        \
    do {                                                       \
        gl_lds(Ag + (k0), &As[(b)*AB + lA0]);                  \
        gl_lds(Ag + (size_t)64 * K + (k0), &As[(b)*AB + lA1]); \
        gl_lds(Wg + (k0), &Ws[(b)*WB + lA0]);                  \
    } while (0)

#define COMPUTE_PR(b)                                                          \
    do {                                                                       \
        bf16x8 af[4], wf[2];                                                   \
        _Pragma("unroll") for (int i = 0; i < 4; ++i)                          \
            af[i] = *(const bf16x8*)&As[(b)*AB + (arow + i * 16) * BK + kq];   \
        _Pragma("unroll") for (int j = 0; j < 2; ++j)                          \
            wf[j] = *(const bf16x8*)&Ws[(b)*WB + (wrow + j * 16) * BK + kq];   \
        _Pragma("unroll") for (int i = 0; i < 4; ++i)                          \
            _Pragma("unroll") for (int j = 0; j < 2; ++j)                      \
                acc[i][j] = __builtin_amdgcn_mfma_f32_16x16x32_bf16(           \
                    af[i], wf[j], acc[i][j], 0, 0, 0);                         \
    } while (0)

    STAGE_PR(0, 0);
    __syncthreads();
    for (int k0 = 0; k0 < K; k0 += 2 * BK) {
        STAGE_PR(1, k0 + BK);
        COMPUTE_PR(0);
        __syncthreads();
        if (k0 + 2 * BK < K) STAGE_PR(0, k0 + 2 * BK);
        COMPUTE_PR(1);
        __syncthreads();
    }
#undef STAGE_PR
#undef COMPUTE_PR

    const int rq = (lane >> 4) * 4;
#pragma unroll
    for (int i = 0; i < 4; ++i) {
        const size_t rbase = tileM + waveM + i * 16 + rq;
#pragma unroll
        for (int j = 0; j < 2; ++j) {
            const size_t n = tileN + waveN + (lane & 15) + j * 16;
#pragma unroll
            for (int v = 0; v < 4; ++v)
                out[(rbase + v) * 512 + n] = acc[i][j][v];
        }
    }
}

// ============ launch ============
extern "C" void kernel_launch(void* const* d_in, const int* in_sizes, int n_in,
                              void* d_out, int out_size, void* d_ws, size_t ws_size,
                              hipStream_t stream) {
    const float* input  = (const float*)d_in[0];
    const float* hx     = (const float*)d_in[1];
    const float* cx     = (const float*)d_in[2];
    const float* w_x    = (const float*)d_in[3];
    const float* b_x    = (const float*)d_in[4];
    const float* w_h    = (const float*)d_in[5];
    const float* b_h    = (const float*)d_in[6];
    const float* w_proj = (const float*)d_in[7];

    constexpr int H = 2048, P = 512, B = 8192;

    char* ws = (char*)d_ws;
    u16* Ahi = (u16*)(ws);                 // [8192,1536] 25,165,824
    u16* Alo = (u16*)(ws + 25165824);      // [8192,1536] 25,165,824
    u16* Whi = (u16*)(ws + 50331648);      // [8192,1536] 25,165,824
    u16* Wlo = (u16*)(ws + 75497472);      // [4096,1536] 12,582,912
    u16* U   = (u16*)(ws + 155189248);     // [8192,2048] 33,554,432
    u16* Wp  = (u16*)(ws + 188743680);     // [512,2048]   2,097,152

    float* ht = (float*)d_out;
    float* ct = (float*)d_out + (size_t)B * P;

    pack_A<<<B, 384, 0, stream>>>(input, hx, Ahi, Alo);
    pack_W<<<4 * H, 384, 0, stream>>>(w_x, w_h, Whi, Wlo);
    pack_flat_bf16<<<(P * H / 4) / 256, 256, 0, stream>>>(w_proj, Wp);

    gemm_gates_cell<<<2048, 256, 0, stream>>>(Ahi, Alo, Whi, Wlo, b_x, b_h,
                                              cx, ct, U);
    gemm_proj<<<dim3(8, 64), 256, 0, stream>>>(U, Wp, ht);
}